// Round 18
// baseline (11586.789 us; speedup 1.0000x reference)
//
#include <hip/hip_runtime.h>

typedef _Float16 f16;
typedef _Float16 h2 __attribute__((ext_vector_type(2)));
typedef float fv4 __attribute__((ext_vector_type(4)));

#define BB 64
#define UU 256
#define RRR 5
#define NQUAD 4

// ---- h2-unit offsets (weights, pair-interleaved [K/2][N]); h2 = 4 bytes ----
constexpr size_t O_WP2T = 10240;    // N=128 K=256
constexpr size_t O_WAIH = 26624;    // N=768 K=128
constexpr size_t O_WAHH = 75776;    // N=768 K=256
constexpr size_t O_WQP  = 174080;   // N=512 K=256 (W2*2log2e | Wproj[:,0:256])
constexpr size_t O_WPC  = 239616;   // N=256 K=256 (Wproj[:,256:512])
constexpr size_t O_W1IH = 272384;   // N=768 K=256
constexpr size_t O_W1HH = 370688;
constexpr size_t O_W2IH = 468992;
constexpr size_t O_W2HH = 567296;
constexpr size_t O_WOUT = 665600;   // N=400 K=256 -> weights end 716800 h2
// ---- float-unit offsets ----
constexpr size_t OF_BQP = 716800;   // 512 floats (0|bproj)
constexpr size_t OF_W1T = 717312;   // 65536 floats
// ---- half-unit offsets ----
constexpr size_t OH_KEYS = 1565696;             // 64*1000*256 halfs (pre-scaled)
constexpr size_t OH_MEM  = OH_KEYS + 16384000;
// ---- cross-block exchange (float/int units) ----
constexpr size_t OF_CTXP  = 17166848;  // ctx_part [64][2][4][256] floats
constexpr size_t OF_ESUM  = 17297920;  // esum     [64][2][4] floats
constexpr size_t OF_QB    = 17298432;  // qbuf     [64][2][256] floats
constexpr size_t OI_FLAGA = 17331200;  // flagA    [64][256] ints
constexpr size_t OI_FLAGB = 17347584;  // flagB    [64][256] ints
// ---- fused WOUT80->prenet1 ----
constexpr size_t O_WFUSE  = 17364992;  // h2 units: [128][256]
constexpr size_t OF_BFUSE = 17397760;  // 512 floats (bfuse | relu(bp1))
// ---- fused W1_ih @ Wproj[:,256:] (N=768 K=256), pair-interleaved [128][768] ----
constexpr size_t O_W1IHC  = 17398272;  // h2 units -> end 17496576 f (~70.0 MB)

#define SCL2LOG2E 2.8853900817779268f

#if defined(__has_builtin)
#if __has_builtin(__builtin_amdgcn_fdot2)
#define USE_FDOT2 1
#endif
#endif

__device__ __forceinline__ float dot2f(h2 a, h2 b, float c){
#ifdef USE_FDOT2
  return __builtin_amdgcn_fdot2(a, b, c, false);
#else
  return c + (float)a[0]*(float)b[0] + (float)a[1]*(float)b[1];
#endif
}

__device__ __forceinline__ float frcp(float x){ return __builtin_amdgcn_rcpf(x); }
__device__ __forceinline__ float fexp2(float x){ return __builtin_amdgcn_exp2f(x); }
__device__ __forceinline__ float fsig(float x){ return frcp(1.0f + fexp2(-1.4426950408889634f*x)); }
__device__ __forceinline__ float ftanh(float x){ return 1.0f - 2.0f*frcp(1.0f + fexp2(SCL2LOG2E*x)); }

// wait: poll RELAXED (no cache-invalidate per iteration), one ACQUIRE at exit.
__device__ __forceinline__ void wait_flag(const int* fl, int target){
  while (__hip_atomic_load(fl, __ATOMIC_RELAXED, __HIP_MEMORY_SCOPE_AGENT) < target){
    __builtin_amdgcn_s_sleep(8);
  }
  (void)__hip_atomic_load(fl, __ATOMIC_ACQUIRE, __HIP_MEMORY_SCOPE_AGENT);
}

// ---------------- setup kernels ----------------
__global__ void k_tr_hx(const float* __restrict__ src, int srcK, int kbase,
                        h2* __restrict__ dst, int N, int K, int Ntot, int coloff,
                        float scale){
  int idx = blockIdx.x*blockDim.x + threadIdx.x;
  int tot = N*(K/2);
  if (idx < tot){
    int k2 = idx / N, n = idx - k2*N;
    h2 p; p[0]=(f16)(scale*src[n*srcK + kbase + 2*k2]);
    p[1]=(f16)(scale*src[n*srcK + kbase + 2*k2+1]);
    dst[(size_t)k2*Ntot + coloff + n] = p;
  }
}

__global__ void k_transpose(const float* __restrict__ src, float* __restrict__ dst, int N, int K){
  int idx = blockIdx.x*blockDim.x + threadIdx.x;
  if (idx < N*K){
    int n = idx / K, k = idx - n*K;
    dst[k*N + n] = src[idx];
  }
}

__global__ void k_biasqp(const float* __restrict__ bproj, float* __restrict__ dst){
  int i = blockIdx.x*blockDim.x + threadIdx.x;
  if (i < 512) dst[i] = (i < 256) ? 0.f : bproj[i-256];
}

// Wfuse[n][m] = sum_mel Wp1[n][mel] * Wout[5*mel+4][m]; pair-interleaved [m/2][n]
__global__ void k_fuse_w(const float* __restrict__ Wp1, const float* __restrict__ Wout,
                         h2* __restrict__ dst){
  int idx = blockIdx.x*blockDim.x + threadIdx.x;
  if (idx < 256*128){
    int k2 = idx >> 8;       // m-pair 0..127
    int n  = idx & 255;
    float s0=0.f, s1=0.f;
    for (int mel=0; mel<80; ++mel){
      float wp = Wp1[n*80+mel];
      const float* wr = Wout + (size_t)(5*mel+4)*256;
      s0 += wp * wr[2*k2];
      s1 += wp * wr[2*k2+1];
    }
    h2 p; p[0]=(f16)s0; p[1]=(f16)s1;
    dst[(size_t)k2*256 + n] = p;
  }
}

__global__ void k_fuse_b(const float* __restrict__ Wp1, const float* __restrict__ bout,
                         const float* __restrict__ bp1, float* __restrict__ dst){
  int n = blockIdx.x*blockDim.x + threadIdx.x;
  if (n < 256){
    float s = bp1[n];
    for (int mel=0; mel<80; ++mel) s += Wp1[n*80+mel]*bout[5*mel+4];
    dst[n] = s;
  }
}

// W1IHC[n][m] = sum_u W1_ih[n][u] * Wproj[u][256+m]; pair-interleaved [m/2][768]
__global__ void k_w1ihc(const float* __restrict__ W1_ih, const float* __restrict__ Wproj,
                        h2* __restrict__ dst){
  int idx = blockIdx.x*blockDim.x + threadIdx.x;
  if (idx < 768*128){
    int k2 = idx / 768, n = idx - k2*768;
    const float* wr = W1_ih + (size_t)n*256;
    float s0=0.f, s1=0.f;
    for (int u=0; u<256; ++u){
      float w = wr[u];
      s0 += w * Wproj[(size_t)u*512 + 256 + 2*k2];
      s1 += w * Wproj[(size_t)u*512 + 256 + 2*k2 + 1];
    }
    h2 p; p[0]=(f16)s0; p[1]=(f16)s1;
    dst[(size_t)k2*768 + n] = p;
  }
}

// initx1[n] = relu(bp1[n])
__global__ void k_initx1(const float* __restrict__ bp1, float* __restrict__ dst){
  int n = blockIdx.x*blockDim.x + threadIdx.x;
  if (n < 256) dst[n] = fmaxf(bp1[n], 0.f);
}

__global__ void k_zero(int* __restrict__ p, int n){
  int i = blockIdx.x*blockDim.x + threadIdx.x;
  if (i < n) p[i] = 0;
}

__global__ void k_memh(const float* __restrict__ src, f16* __restrict__ dst, int n8){
  int i = blockIdx.x*blockDim.x + threadIdx.x;
  if (i < n8){
    const float4* s = reinterpret_cast<const float4*>(src) + 2*(size_t)i;
    float4 f0 = s[0], f1 = s[1];
    union { f16 h[8]; float4 v; } u;
    u.h[0]=(f16)f0.x; u.h[1]=(f16)f0.y; u.h[2]=(f16)f0.z; u.h[3]=(f16)f0.w;
    u.h[4]=(f16)f1.x; u.h[5]=(f16)f1.y; u.h[6]=(f16)f1.z; u.h[7]=(f16)f1.w;
    reinterpret_cast<float4*>(dst)[i] = u.v;
  }
}

// keys[b][t][c] = 2log2e * sum_u mem[b][t][u]*W1[c][u]; fp16 out
__global__ __launch_bounds__(256) void k_keys(const float* __restrict__ mem,
      const float* __restrict__ W1t, f16* __restrict__ keys, int T)
{
  const int b = blockIdx.z;
  const int tbase = blockIdx.x * 128;
  const int cbase = blockIdx.y * 128;
  const int tid = threadIdx.x;
  const int rt = tid >> 4, ct = tid & 15;
  const float* memb = mem + (size_t)b*T*UU;

  float acc[8][8];
  #pragma unroll
  for (int i=0;i<8;i++){
    #pragma unroll
    for (int j=0;j<8;j++) acc[i][j]=0.f;
  }
  const float* arow[8];
  #pragma unroll
  for (int i=0;i<8;i++){
    int t = tbase + rt*8 + i;
    arow[i] = memb + (size_t)(t < T ? t : T-1)*UU;
  }
  const float* wcol = W1t + cbase + ct*8;

  for (int k=0;k<UU;k+=4){
    float w8[4][8];
    #pragma unroll
    for (int kk=0;kk<4;kk++){
      float4 lo = *reinterpret_cast<const float4*>(wcol + (size_t)(k+kk)*UU);
      float4 hi = *reinterpret_cast<const float4*>(wcol + (size_t)(k+kk)*UU + 4);
      w8[kk][0]=lo.x; w8[kk][1]=lo.y; w8[kk][2]=lo.z; w8[kk][3]=lo.w;
      w8[kk][4]=hi.x; w8[kk][5]=hi.y; w8[kk][6]=hi.z; w8[kk][7]=hi.w;
    }
    #pragma unroll
    for (int i=0;i<8;i++){
      float4 a = *reinterpret_cast<const float4*>(arow[i] + k);
      float a4[4] = {a.x, a.y, a.z, a.w};
      #pragma unroll
      for (int kk=0;kk<4;kk++){
        #pragma unroll
        for (int j=0;j<8;j++) acc[i][j] += a4[kk]*w8[kk][j];
      }
    }
  }
  #pragma unroll
  for (int i=0;i<8;i++){
    int t = tbase + rt*8 + i;
    if (t < T){
      f16* dst = keys + (size_t)b*T*UU + (size_t)t*UU + cbase + ct*8;
      union { f16 h[8]; float4 v; } u;
      #pragma unroll
      for (int j=0;j<8;j++) u.h[j] = (f16)(acc[i][j]*SCL2LOG2E);
      *reinterpret_cast<float4*>(dst) = u.v;
    }
  }
}

// ---------------- 2-way in-wave K-split GEMV ----------------
__device__ __attribute__((noinline)) void gemv_shfl(
    const h2* __restrict__ W, const h2* __restrict__ in,
    const float* __restrict__ bias, float* __restrict__ destf, h2* __restrict__ desth,
    int K2, int Nf4, int act, int local)
{
  const int lane = local & 63;
  const int half = lane >> 5;
  int col = (local >> 6)*32 + (lane & 31);
  const bool valid = col < Nf4;
  if (!valid) col = 0;
  const int kh = K2 >> 1;
  const float4* w = reinterpret_cast<const float4*>(W) + (size_t)(half*kh)*Nf4 + col;
  const h2* ia = in + half*kh;
  float a0=0.f, a1=0.f, a2=0.f, a3=0.f;
  #pragma unroll 8
  for (int it = 0; it < kh; ++it){
    float4 wp = w[(size_t)it*Nf4];
    h2 a = ia[it];
    const h2* wh = reinterpret_cast<const h2*>(&wp);
    a0 = dot2f(wh[0], a, a0);
    a1 = dot2f(wh[1], a, a1);
    a2 = dot2f(wh[2], a, a2);
    a3 = dot2f(wh[3], a, a3);
  }
  a0 += __shfl_xor(a0, 32, 64);
  a1 += __shfl_xor(a1, 32, 64);
  a2 += __shfl_xor(a2, 32, 64);
  a3 += __shfl_xor(a3, 32, 64);
  if (half == 0 && valid){
    if (bias){
      const float4 bv = reinterpret_cast<const float4*>(bias)[col];
      a0+=bv.x; a1+=bv.y; a2+=bv.z; a3+=bv.w;
    }
    if (act == 1){
      a0=fmaxf(a0,0.f); a1=fmaxf(a1,0.f); a2=fmaxf(a2,0.f); a3=fmaxf(a3,0.f);
    } else if (act == 2){
      const float4 d = reinterpret_cast<float4*>(destf)[col];
      a0+=d.x; a1+=d.y; a2+=d.z; a3+=d.w;
    }
    if (destf){
      float4 r; r.x=a0; r.y=a1; r.z=a2; r.w=a3;
      reinterpret_cast<float4*>(destf)[col] = r;
    }
    if (desth){
      h2 p0; p0[0]=(f16)a0; p0[1]=(f16)a1;
      h2 p1; p1[0]=(f16)a2; p1[1]=(f16)a3;
      desth[2*col] = p0; desth[2*col+1] = p1;
    }
  }
}

// ---------------- 4-way in-wave K-split GEMV (cols/wave = 16) ----------------
__device__ __attribute__((noinline)) void gemv_shfl4(
    const h2* __restrict__ W, const h2* __restrict__ in,
    const float* __restrict__ bias, float* __restrict__ destf, h2* __restrict__ desth,
    int K2, int Nf4, int act, int local)
{
  const int lane = local & 63;
  const int qtr  = lane >> 4;
  int col = (local >> 6)*16 + (lane & 15);
  const bool valid = col < Nf4;
  if (!valid) col = 0;
  const int kq = K2 >> 2;
  const float4* w = reinterpret_cast<const float4*>(W) + (size_t)(qtr*kq)*Nf4 + col;
  const h2* ia = in + qtr*kq;
  float a0=0.f, a1=0.f, a2=0.f, a3=0.f;
  #pragma unroll 8
  for (int it = 0; it < kq; ++it){
    float4 wp = w[(size_t)it*Nf4];
    h2 a = ia[it];
    const h2* wh = reinterpret_cast<const h2*>(&wp);
    a0 = dot2f(wh[0], a, a0);
    a1 = dot2f(wh[1], a, a1);
    a2 = dot2f(wh[2], a, a2);
    a3 = dot2f(wh[3], a, a3);
  }
  a0 += __shfl_xor(a0, 16, 64); a1 += __shfl_xor(a1, 16, 64);
  a2 += __shfl_xor(a2, 16, 64); a3 += __shfl_xor(a3, 16, 64);
  a0 += __shfl_xor(a0, 32, 64); a1 += __shfl_xor(a1, 32, 64);
  a2 += __shfl_xor(a2, 32, 64); a3 += __shfl_xor(a3, 32, 64);
  if (qtr == 0 && valid){
    if (bias){
      const float4 bv = reinterpret_cast<const float4*>(bias)[col];
      a0+=bv.x; a1+=bv.y; a2+=bv.z; a3+=bv.w;
    }
    if (act == 1){
      a0=fmaxf(a0,0.f); a1=fmaxf(a1,0.f); a2=fmaxf(a2,0.f); a3=fmaxf(a3,0.f);
    } else if (act == 2){
      const float4 d = reinterpret_cast<float4*>(destf)[col];
      a0+=d.x; a1+=d.y; a2+=d.z; a3+=d.w;
    }
    if (destf){
      float4 r; r.x=a0; r.y=a1; r.z=a2; r.w=a3;
      reinterpret_cast<float4*>(destf)[col] = r;
    }
    if (desth){
      h2 p0; p0[0]=(f16)a0; p0[1]=(f16)a1;
      h2 p1; p1[0]=(f16)a2; p1[1]=(f16)a3;
      desth[2*col] = p0; desth[2*col+1] = p1;
    }
  }
}

// ---------------- 8-way in-wave K-split GEMV (cols/wave = 8) ----------------
__device__ __attribute__((noinline)) void gemv_shfl8(
    const h2* __restrict__ W, const h2* __restrict__ in,
    const float* __restrict__ bias, float* __restrict__ destf, h2* __restrict__ desth,
    int K2, int Nf4, int act, int local)
{
  const int lane = local & 63;
  const int oct  = lane >> 3;            // 0..7
  int col = (local >> 6)*8 + (lane & 7);
  const bool valid = col < Nf4;
  if (!valid) col = 0;
  const int kq = K2 >> 3;
  const float4* w = reinterpret_cast<const float4*>(W) + (size_t)(oct*kq)*Nf4 + col;
  const h2* ia = in + oct*kq;
  float a0=0.f, a1=0.f, a2=0.f, a3=0.f;
  #pragma unroll 8
  for (int it = 0; it < kq; ++it){
    float4 wp = w[(size_t)it*Nf4];
    h2 a = ia[it];
    const h2* wh = reinterpret_cast<const h2*>(&wp);
    a0 = dot2f(wh[0], a, a0);
    a1 = dot2f(wh[1], a, a1);
    a2 = dot2f(wh[2], a, a2);
    a3 = dot2f(wh[3], a, a3);
  }
  a0 += __shfl_xor(a0,  8, 64); a1 += __shfl_xor(a1,  8, 64);
  a2 += __shfl_xor(a2,  8, 64); a3 += __shfl_xor(a3,  8, 64);
  a0 += __shfl_xor(a0, 16, 64); a1 += __shfl_xor(a1, 16, 64);
  a2 += __shfl_xor(a2, 16, 64); a3 += __shfl_xor(a3, 16, 64);
  a0 += __shfl_xor(a0, 32, 64); a1 += __shfl_xor(a1, 32, 64);
  a2 += __shfl_xor(a2, 32, 64); a3 += __shfl_xor(a3, 32, 64);
  if (oct == 0 && valid){
    if (bias){
      const float4 bv = reinterpret_cast<const float4*>(bias)[col];
      a0+=bv.x; a1+=bv.y; a2+=bv.z; a3+=bv.w;
    }
    if (act == 1){
      a0=fmaxf(a0,0.f); a1=fmaxf(a1,0.f); a2=fmaxf(a2,0.f); a3=fmaxf(a3,0.f);
    } else if (act == 2){
      const float4 d = reinterpret_cast<float4*>(destf)[col];
      a0+=d.x; a1+=d.y; a2+=d.z; a3+=d.w;
    }
    if (destf){
      float4 r; r.x=a0; r.y=a1; r.z=a2; r.w=a3;
      reinterpret_cast<float4*>(destf)[col] = r;
    }
    if (desth){
      h2 p0; p0[0]=(f16)a0; p0[1]=(f16)a1;
      h2 p1; p1[0]=(f16)a2; p1[1]=(f16)a3;
      desth[2*col] = p0; desth[2*col+1] = p1;
    }
  }
}

__device__ __attribute__((noinline)) void gru_gate(
    const float* __restrict__ gi, const float* __restrict__ gh,
    float* __restrict__ h, h2* __restrict__ hh2,
    const float* __restrict__ addsrc, float* __restrict__ sumf,
    h2* __restrict__ sumh, int tid)
{
  if (tid < 128){
    float hn[2], sm[2] = {0.f, 0.f};
    #pragma unroll
    for (int d=0; d<2; ++d){
      int e = 2*tid + d;
      float r = fsig(gi[e] + gh[e]);
      float z = fsig(gi[256+e] + gh[256+e]);
      float n = ftanh(gi[512+e] + r*gh[512+e]);
      hn[d] = (1.f - z)*n + z*h[e];
      h[e] = hn[d];
      if (addsrc){ sm[d] = addsrc[e] + hn[d]; if (sumf) sumf[e] = sm[d]; }
    }
    h2 p; p[0]=(f16)hn[0]; p[1]=(f16)hn[1];
    hh2[tid] = p;
    if (addsrc && sumh){ h2 q; q[0]=(f16)sm[0]; q[1]=(f16)sm[1]; sumh[tid] = q; }
  }
  __syncthreads();
}

// ---------------- persistent decoder: owner (quad0) + attention workers ----------------
__global__ __launch_bounds__(1024) void k_decode(
    const h2* __restrict__ wts, const float* __restrict__ wsf,
    const f16* __restrict__ keysg, const f16* __restrict__ memg,
    float* __restrict__ ctxp, float* __restrict__ esum, float* __restrict__ qbuf,
    int* __restrict__ flagA, int* __restrict__ flagB,
    const float* __restrict__ bp2, const float* __restrict__ vvec,
    const float* __restrict__ ba_ih, const float* __restrict__ ba_hh,
    const float* __restrict__ b1_ih, const float* __restrict__ b1_hh,
    const float* __restrict__ b2_ih, const float* __restrict__ b2_hh,
    const float* __restrict__ bout,
    float* __restrict__ out, int T, int steps)
{
  __shared__ __align__(16) float s_red[4096];
  __shared__ __align__(16) float s_sc[1024];
  __shared__ __align__(16) float s_gi[768];
  __shared__ __align__(16) float s_ghP[2][768];  // parity-buffered Wa_hh@h + ba_hh (prefetched)
  __shared__ __align__(16) float s_gh1[768];
  __shared__ __align__(16) float s_gh2[768];
  __shared__ __align__(16) float s_q[512];       // [0:256]=q', [256:512]=g1in
  __shared__ __align__(16) h2    s_qh[256];      // h2 copy of s_q (g1in_dt in [128:256])
  __shared__ __align__(16) float s_ha[256];
  __shared__ __align__(16) float s_g1h[256];
  __shared__ __align__(16) float s_g2h[256];
  __shared__ __align__(16) float s_g2in[256];
  __shared__ __align__(16) float s_y[400];
  __shared__ __align__(16) h2    s_hah[128], s_g1hh[128], s_g2hh[128];
  __shared__ __align__(16) h2    s_g2inh[128], s_s2h[128];
  __shared__ __align__(16) h2    s_x1h[128], s_xh[64], s_ctxh[128];
  __shared__ float s_wred[16];

  const int b    = blockIdx.x & 63;
  const int quad = blockIdx.x >> 6;
  const int tid = threadIdx.x;
  const int lane = tid & 63;
  const int wid = tid >> 6;
  const int half_id = lane >> 5;
  const int cl = lane & 31;

  const f16* keyb = keysg + (size_t)b*T*UU;
  const f16* memb = memg  + (size_t)b*T*UU;
  float* outb = out + (size_t)b*80*(steps*RRR);

  // slice bounds: owner ~10% (its overlap window also runs 4 prefetch GEMVs),
  // workers split the rest; all boundaries even (2 rows/wave loop).
  const int ownEnd = ((T*10)/100) & ~1;
  int tq0, tq1;
  if (quad == 0){ tq0 = 0; tq1 = ownEnd; }
  else {
    tq0 = (quad==1) ? ownEnd : (ownEnd + ((T-ownEnd)*(quad-1))/3) & ~1;
    tq1 = (quad==3) ? T      : (ownEnd + ((T-ownEnd)*quad)/3) & ~1;
  }

  float v8[8], m8[8];
  #pragma unroll
  for (int j=0;j<8;j++){ v8[j] = vvec[cl*8+j]; m8[j] = -2.0f*v8[j]; }
  float sumv = 0.f;
  #pragma unroll
  for (int j=0;j<8;j++) sumv += v8[j];
  #pragma unroll
  for (int o=1;o<32;o<<=1) sumv += __shfl_xor(sumv, o);

  // attention slice: scores -> exp -> ctx partials -> publish (ctxp, esum)
  auto attn_slice = [&](int par){
    {
      float q8[8];
      #pragma unroll
      for (int j=0;j<8;j++) q8[j] = s_q[cl*8+j];
      float rs = 0.f;
      for (int t0 = tq0 + wid*2; t0 < tq1; t0 += 32){
        int t = t0 + half_id;
        fv4 kv = *(reinterpret_cast<const fv4*>(keyb + (size_t)t*UU) + cl);
        const h2* kh = reinterpret_cast<const h2*>(&kv);
        float acc = 0.f;
        #pragma unroll
        for (int p=0;p<4;p++){
          float t0f = (float)kh[p][0] + q8[2*p];
          float t1f = (float)kh[p][1] + q8[2*p+1];
          acc = fmaf(m8[2*p],   frcp(1.f + fexp2(t0f)), acc);
          acc = fmaf(m8[2*p+1], frcp(1.f + fexp2(t1f)), acc);
        }
        #pragma unroll
        for (int o=1;o<32;o<<=1) acc += __shfl_xor(acc, o);
        float e = __expf(sumv + acc);
        if (cl == 0) s_sc[t] = e;
        rs += e;
      }
      rs += __shfl_xor(rs, 32);
      if (lane==0) s_wred[wid] = rs;
    }
    __syncthreads();
    {
      float c8[8] = {0.f,0.f,0.f,0.f,0.f,0.f,0.f,0.f};
      for (int t0 = tq0 + wid*2; t0 < tq1; t0 += 32){
        int t = t0 + half_id;
        float wgt = s_sc[t];
        fv4 mv = *(reinterpret_cast<const fv4*>(memb + (size_t)t*UU) + cl);
        const h2* mh = reinterpret_cast<const h2*>(&mv);
        #pragma unroll
        for (int p=0;p<4;p++){
          c8[2*p  ] += wgt*(float)mh[p][0];
          c8[2*p+1] += wgt*(float)mh[p][1];
        }
      }
      #pragma unroll
      for (int j=0;j<8;j++) c8[j] += __shfl_xor(c8[j], 32);
      if (half_id == 0){
        float4 lo; lo.x=c8[0]; lo.y=c8[1]; lo.z=c8[2]; lo.w=c8[3];
        float4 hi; hi.x=c8[4]; hi.y=c8[5]; hi.z=c8[6]; hi.w=c8[7];
        *reinterpret_cast<float4*>(s_red + wid*256 + cl*8)     = lo;
        *reinterpret_cast<float4*>(s_red + wid*256 + cl*8 + 4) = hi;
      }
    }
    __syncthreads();
    {
      float* cp = ctxp + (((size_t)b*2 + par)*NQUAD + quad)*256;
      if (tid < 128){
        float a = 0.f, c = 0.f;
        #pragma unroll
        for (int w=0; w<16; ++w){
          a += s_red[w*256 + 2*tid];
          c += s_red[w*256 + 2*tid+1];
        }
        cp[2*tid]   = a;
        cp[2*tid+1] = c;
      }
      if (tid == 0){
        float tot = 0.f;
        #pragma unroll
        for (int w=0; w<16; ++w) tot += s_wred[w];
        esum[((size_t)b*2 + par)*NQUAD + quad] = tot;
      }
    }
    __syncthreads();
  };

  if (quad != 0){
    // ---------------- worker: attention only ----------------
    for (int step = 0; step < steps; ++step){
      const int par = step & 1;
      if (tid == 0) wait_flag(flagA + b*256 + step, 1);
      __syncthreads();
      if (tid < 256)
        s_q[tid] = __hip_atomic_load(qbuf + ((size_t)b*2 + par)*256 + tid,
                                     __ATOMIC_RELAXED, __HIP_MEMORY_SCOPE_AGENT);
      __syncthreads();
      attn_slice(par);
      if (tid == 0){
        __threadfence();
        __hip_atomic_fetch_add(flagB + b*256 + step, 1, __ATOMIC_RELEASE, __HIP_MEMORY_SCOPE_AGENT);
      }
      __syncthreads();
    }
    return;
  }

  // ---------------- owner ----------------
  if (tid < 128){
    s_ha[2*tid]=0.f; s_ha[2*tid+1]=0.f;
    s_g1h[2*tid]=0.f; s_g1h[2*tid+1]=0.f;
    s_g2h[2*tid]=0.f; s_g2h[2*tid+1]=0.f;
    h2 z; z[0]=(f16)0.f; z[1]=(f16)0.f;
    s_hah[tid]=z; s_g1hh[tid]=z; s_g2hh[tid]=z;
    // x1(0) = relu(bp1) from the init buffer at OF_BFUSE+256
    const float* ix = wsf + OF_BFUSE + 256;
    h2 p; p[0] = (f16)ix[2*tid]; p[1] = (f16)ix[2*tid+1];
    s_x1h[tid] = p;
  }
  for (int i = tid; i < 768; i += 1024) s_ghP[0][i] = ba_hh[i];
  __syncthreads();

  for (int step = 0; step < steps; ++step){
    const int par = step & 1;
    // part1: prenet2 (x1 -> x): 8-way, 256 thr
    if (tid < 256) gemv_shfl8(wts+O_WP2T, s_x1h, bp2, nullptr, s_xh, 128, 32, 1, tid);
    __syncthreads();
    // WAIH (K2=64): 4-way, 768 thr
    if (tid < 768) gemv_shfl4(wts+O_WAIH, s_xh, ba_ih, s_gi, nullptr, 64, 192, 0, tid);
    __syncthreads();
    // gate_a with PREFETCHED gha (s_ghP[par])
    gru_gate(s_gi, s_ghP[par], s_ha, s_hah, nullptr, nullptr, nullptr, tid);
    // WQP: q' | g1in_dt: 8-way, all 1024 thr; also emit h2 copy (s_qh)
    gemv_shfl8(wts+O_WQP, s_hah, wsf+OF_BQP, s_q, s_qh, 128, 128, 0, tid);
    __syncthreads();
    // publish q', release flag A
    if (tid < 256)
      qbuf[((size_t)b*2 + par)*256 + tid] = s_q[tid];
    __syncthreads();
    if (tid == 0){
      __threadfence();
      __hip_atomic_fetch_add(flagA + b*256 + step, 1, __ATOMIC_RELEASE, __HIP_MEMORY_SCOPE_AGENT);
    }
    // overlap window:
    //  - WAHH prefetch for NEXT step (d_t(s) just computed)
    //  - W1HH || W2HH (needed at tail gates)
    //  - gi1_dt = W1_ih @ g1in_dt + b1_ih  (ctx-independent half of gi1)
    if (tid < 768) gemv_shfl4(wts+O_WAHH, s_hah, ba_hh, s_ghP[par^1], nullptr, 128, 192, 0, tid);
    if (tid < 384)      gemv_shfl(wts+O_W1HH, s_g1hh, b1_hh, s_gh1, nullptr, 128, 192, 0, tid);
    else if (tid < 768) gemv_shfl(wts+O_W2HH, s_g2hh, b2_hh, s_gh2, nullptr, 128, 192, 0, tid-384);
    if (tid < 768) gemv_shfl4(wts+O_W1IH, s_qh+128, b1_ih, s_gi, nullptr, 128, 192, 0, tid);
    attn_slice(par);
    if (tid == 0){
      __threadfence();
      __hip_atomic_fetch_add(flagB + b*256 + step, 1, __ATOMIC_RELEASE, __HIP_MEMORY_SCOPE_AGENT);
      wait_flag(flagB + b*256 + step, NQUAD);
    }
    __syncthreads();
    // combine
    if (tid < 128){
      const float* cp0 = ctxp + ((size_t)b*2 + par)*NQUAD*256;
      const float* es0 = esum + ((size_t)b*2 + par)*NQUAD;
      float es = 0.f;
      #pragma unroll
      for (int q4=0;q4<NQUAD;q4++)
        es += __hip_atomic_load(&es0[q4], __ATOMIC_RELAXED, __HIP_MEMORY_SCOPE_AGENT);
      float inv = frcp(es);
      float a = 0.f, c = 0.f;
      #pragma unroll
      for (int q4=0;q4<NQUAD;q4++){
        a += __hip_atomic_load(&cp0[q4*256 + 2*tid],   __ATOMIC_RELAXED, __HIP_MEMORY_SCOPE_AGENT);
        c += __hip_atomic_load(&cp0[q4*256 + 2*tid+1], __ATOMIC_RELAXED, __HIP_MEMORY_SCOPE_AGENT);
      }
      h2 p; p[0]=(f16)(a*inv); p[1]=(f16)(c*inv);
      s_ctxh[tid] = p;
    }
    __syncthreads();
    // stage A: gi1 += W1IHC@ctx (768 thr) || g1in += WPC@ctx (256 thr)
    if (tid < 768) gemv_shfl4(wts+O_W1IHC, s_ctxh, nullptr, s_gi, nullptr, 128, 192, 2, tid);
    else           gemv_shfl4(wts+O_WPC,   s_ctxh, nullptr, s_q+256, nullptr, 128, 64, 2, tid-768);
    __syncthreads();
    gru_gate(s_gi, s_gh1, s_g1h, s_g1hh, s_q+256, s_g2in, s_g2inh, tid);
    // W2IH: 4-way (width 192)
    if (tid < 768) gemv_shfl4(wts+O_W2IH, s_g2inh, b2_ih, s_gi, nullptr, 128, 192, 0, tid);
    __syncthreads();
    gru_gate(s_gi, s_gh2, s_g2h, s_g2hh, s_g2in, nullptr, s_s2h, tid);
    // WFUSE (recurrence-critical) 8-way 512 thr || WOUT (output only) 4-way 448 thr
    if (tid < 512)      gemv_shfl8(wts+O_WFUSE, s_s2h, wsf+OF_BFUSE, nullptr, s_x1h, 128, 64, 1, tid);
    else if (tid < 960) gemv_shfl4(wts+O_WOUT,  s_s2h, bout, s_y, nullptr, 128, 100, 0, tid-512);
    __syncthreads();
    // scatter
    if (tid < 400){
      float val = s_y[tid];
      int mel = tid / 5, rr = tid - mel*5;
      __builtin_nontemporal_store(val, &outb[(size_t)mel*(steps*RRR) + step*RRR + rr]);
    }
    __syncthreads();
  }
}

extern "C" void kernel_launch(void* const* d_in, const int* in_sizes, int n_in,
                              void* d_out, int out_size, void* d_ws, size_t ws_size,
                              hipStream_t stream)
{
  const float* mem  = (const float*)d_in[0];
  const float* Wp1  = (const float*)d_in[1];
  const float* bp1  = (const float*)d_in[2];
  const float* Wp2  = (const float*)d_in[3];
  const float* bp2  = (const float*)d_in[4];
  const float* W1   = (const float*)d_in[5];
  const float* W2   = (const float*)d_in[6];
  const float* vv   = (const float*)d_in[7];
  const float* Wa_ih= (const float*)d_in[8];
  const float* Wa_hh= (const float*)d_in[9];
  const float* ba_ih= (const float*)d_in[10];
  const float* ba_hh= (const float*)d_in[11];
  const float* W1_ih= (const float*)d_in[12];
  const float* W1_hh= (const float*)d_in[13];
  const float* b1_ih= (const float*)d_in[14];
  const float* b1_hh= (const float*)d_in[15];
  const float* W2_ih= (const float*)d_in[16];
  const float* W2_hh= (const float*)d_in[17];
  const float* b2_ih= (const float*)d_in[18];
  const float* b2_hh= (const float*)d_in[19];
  const float* Wproj= (const float*)d_in[20];
  const float* bproj= (const float*)d_in[21];
  const float* Wout = (const float*)d_in[22];
  const float* bout = (const float*)d_in[23];

  h2*  wsH2 = (h2*)d_ws;
  f16* wsF16= (f16*)d_ws;
  float* wsF = (float*)d_ws;
  int*  wsI = (int*)d_ws;
  int T = in_sizes[0] / (BB*UU);
  int steps = T / RRR;

  auto tr = [&](const float* src, int srcK, int kbase, size_t off, int N, int K,
                int Ntot, int coloff, float scale){
    int total = N*(K/2);
    k_tr_hx<<<dim3((total+255)/256), dim3(256), 0, stream>>>(
        src, srcK, kbase, wsH2 + off, N, K, Ntot, coloff, scale);
  };
  tr(Wp2,   256, 0, O_WP2T, 128, 256, 128, 0, 1.f);
  tr(Wa_ih, 128, 0, O_WAIH, 768, 128, 768, 0, 1.f);
  tr(Wa_hh, 256, 0, O_WAHH, 768, 256, 768, 0, 1.f);
  tr(W2,    256, 0, O_WQP,  256, 256, 512, 0, SCL2LOG2E);
  tr(Wproj, 512, 0, O_WQP,  256, 256, 512, 256, 1.f);
  tr(Wproj, 512, 256, O_WPC, 256, 256, 256, 0, 1.f);
  tr(W1_ih, 256, 0, O_W1IH, 768, 256, 768, 0, 1.f);
  tr(W1_hh, 256, 0, O_W1HH, 768, 256, 768, 0, 1.f);
  tr(W2_ih, 256, 0, O_W2IH, 768, 256, 768, 0, 1.f);
  tr(W2_hh, 256, 0, O_W2HH, 768, 256, 768, 0, 1.f);
  tr(Wout,  256, 0, O_WOUT, 400, 256, 400, 0, 1.f);

  k_biasqp<<<dim3(2), dim3(256), 0, stream>>>(bproj, wsF + OF_BQP);
  k_transpose<<<dim3((256*256+255)/256), dim3(256), 0, stream>>>(W1, wsF + OF_W1T, 256, 256);
  k_zero<<<dim3(128), dim3(256), 0, stream>>>(wsI + OI_FLAGA, 2*64*256);
  k_fuse_w<<<dim3((256*128+255)/256), dim3(256), 0, stream>>>(Wp1, Wout, wsH2 + O_WFUSE);
  k_fuse_b<<<dim3(1), dim3(256), 0, stream>>>(Wp1, bout, bp1, wsF + OF_BFUSE);
  k_initx1<<<dim3(1), dim3(256), 0, stream>>>(bp1, wsF + OF_BFUSE + 256);
  k_w1ihc<<<dim3((768*128+255)/256), dim3(256), 0, stream>>>(W1_ih, Wproj, wsH2 + O_W1IHC);

  int n8 = (BB*T*UU)/8;
  k_memh<<<dim3((n8+255)/256), dim3(256), 0, stream>>>(mem, wsF16 + OH_MEM, n8);
  k_keys<<<dim3((T+127)/128, UU/128, BB), dim3(256), 0, stream>>>(mem, wsF + OF_W1T, wsF16 + OH_KEYS, T);

  k_decode<<<dim3(BB*NQUAD), dim3(1024), 0, stream>>>(wsH2, wsF,
      wsF16 + OH_KEYS, wsF16 + OH_MEM,
      wsF + OF_CTXP, wsF + OF_ESUM, wsF + OF_QB,
      wsI + OI_FLAGA, wsI + OI_FLAGB,
      bp2, vv, ba_ih, ba_hh, b1_ih, b1_hh, b2_ih, b2_hh, bout,
      (float*)d_out, T, steps);
}

// Round 19
// 11002.501 us; speedup vs baseline: 1.0531x; 1.0531x over previous
//
#include <hip/hip_runtime.h>

typedef _Float16 f16;
typedef _Float16 h2 __attribute__((ext_vector_type(2)));
typedef float fv4 __attribute__((ext_vector_type(4)));

#define BB 64
#define UU 256
#define RRR 5
#define NQUAD 4

// ---- h2-unit offsets (weights, pair-interleaved [K/2][N]); h2 = 4 bytes ----
constexpr size_t O_WP2T = 10240;    // N=128 K=256
constexpr size_t O_WAIH = 26624;    // N=768 K=128
constexpr size_t O_WAHH = 75776;    // N=768 K=256
constexpr size_t O_WQP  = 174080;   // N=512 K=256 (W2*2log2e | Wproj[:,0:256])
constexpr size_t O_WPC  = 239616;   // N=256 K=256 (Wproj[:,256:512])
constexpr size_t O_W1IH = 272384;   // N=768 K=256
constexpr size_t O_W1HH = 370688;
constexpr size_t O_W2IH = 468992;
constexpr size_t O_W2HH = 567296;
constexpr size_t O_WOUT = 665600;   // N=400 K=256 -> weights end 716800 h2
// ---- float-unit offsets ----
constexpr size_t OF_BQP = 716800;   // 512 floats (0|bproj)
constexpr size_t OF_W1T = 717312;   // 65536 floats
// ---- half-unit offsets ----
constexpr size_t OH_KEYS = 1565696;             // 64*1000*256 halfs (pre-scaled)
constexpr size_t OH_MEM  = OH_KEYS + 16384000;
// ---- cross-block exchange (float/int units) ----
constexpr size_t OF_CTXP  = 17166848;  // ctx_part [64][2][4][256] floats
constexpr size_t OF_ESUM  = 17297920;  // esum     [64][2][4] floats
constexpr size_t OF_QB    = 17298432;  // qbuf     [64][2][256] floats
constexpr size_t OI_FLAGA = 17331200;  // flagA    [64][256] ints
constexpr size_t OI_FLAGB = 17347584;  // flagB    [64][256] ints
// ---- fused WOUT80->prenet1 ----
constexpr size_t O_WFUSE  = 17364992;  // h2 units: [128][256]
constexpr size_t OF_BFUSE = 17397760;  // 512 floats (bfuse | relu(bp1))

#define SCL2LOG2E 2.8853900817779268f

#if defined(__has_builtin)
#if __has_builtin(__builtin_amdgcn_fdot2)
#define USE_FDOT2 1
#endif
#endif

__device__ __forceinline__ float dot2f(h2 a, h2 b, float c){
#ifdef USE_FDOT2
  return __builtin_amdgcn_fdot2(a, b, c, false);
#else
  return c + (float)a[0]*(float)b[0] + (float)a[1]*(float)b[1];
#endif
}

__device__ __forceinline__ float frcp(float x){ return __builtin_amdgcn_rcpf(x); }
__device__ __forceinline__ float fexp2(float x){ return __builtin_amdgcn_exp2f(x); }
__device__ __forceinline__ float fsig(float x){ return frcp(1.0f + fexp2(-1.4426950408889634f*x)); }
__device__ __forceinline__ float ftanh(float x){ return 1.0f - 2.0f*frcp(1.0f + fexp2(SCL2LOG2E*x)); }

// wait: poll RELAXED (no cache-invalidate per iteration), one ACQUIRE at exit.
__device__ __forceinline__ void wait_flag(const int* fl, int target){
  while (__hip_atomic_load(fl, __ATOMIC_RELAXED, __HIP_MEMORY_SCOPE_AGENT) < target){
    __builtin_amdgcn_s_sleep(8);
  }
  (void)__hip_atomic_load(fl, __ATOMIC_ACQUIRE, __HIP_MEMORY_SCOPE_AGENT);
}

// ---------------- setup kernels ----------------
__global__ void k_tr_hx(const float* __restrict__ src, int srcK, int kbase,
                        h2* __restrict__ dst, int N, int K, int Ntot, int coloff,
                        float scale){
  int idx = blockIdx.x*blockDim.x + threadIdx.x;
  int tot = N*(K/2);
  if (idx < tot){
    int k2 = idx / N, n = idx - k2*N;
    h2 p; p[0]=(f16)(scale*src[n*srcK + kbase + 2*k2]);
    p[1]=(f16)(scale*src[n*srcK + kbase + 2*k2+1]);
    dst[(size_t)k2*Ntot + coloff + n] = p;
  }
}

__global__ void k_transpose(const float* __restrict__ src, float* __restrict__ dst, int N, int K){
  int idx = blockIdx.x*blockDim.x + threadIdx.x;
  if (idx < N*K){
    int n = idx / K, k = idx - n*K;
    dst[k*N + n] = src[idx];
  }
}

__global__ void k_biasqp(const float* __restrict__ bproj, float* __restrict__ dst){
  int i = blockIdx.x*blockDim.x + threadIdx.x;
  if (i < 512) dst[i] = (i < 256) ? 0.f : bproj[i-256];
}

// Wfuse[n][m] = sum_mel Wp1[n][mel] * Wout[5*mel+4][m]; pair-interleaved [m/2][n]
__global__ void k_fuse_w(const float* __restrict__ Wp1, const float* __restrict__ Wout,
                         h2* __restrict__ dst){
  int idx = blockIdx.x*blockDim.x + threadIdx.x;
  if (idx < 256*128){
    int k2 = idx >> 8;       // m-pair 0..127
    int n  = idx & 255;
    float s0=0.f, s1=0.f;
    for (int mel=0; mel<80; ++mel){
      float wp = Wp1[n*80+mel];
      const float* wr = Wout + (size_t)(5*mel+4)*256;
      s0 += wp * wr[2*k2];
      s1 += wp * wr[2*k2+1];
    }
    h2 p; p[0]=(f16)s0; p[1]=(f16)s1;
    dst[(size_t)k2*256 + n] = p;
  }
}

__global__ void k_fuse_b(const float* __restrict__ Wp1, const float* __restrict__ bout,
                         const float* __restrict__ bp1, float* __restrict__ dst){
  int n = blockIdx.x*blockDim.x + threadIdx.x;
  if (n < 256){
    float s = bp1[n];
    for (int mel=0; mel<80; ++mel) s += Wp1[n*80+mel]*bout[5*mel+4];
    dst[n] = s;
  }
}

// initx1[n] = relu(bp1[n])
__global__ void k_initx1(const float* __restrict__ bp1, float* __restrict__ dst){
  int n = blockIdx.x*blockDim.x + threadIdx.x;
  if (n < 256) dst[n] = fmaxf(bp1[n], 0.f);
}

__global__ void k_zero(int* __restrict__ p, int n){
  int i = blockIdx.x*blockDim.x + threadIdx.x;
  if (i < n) p[i] = 0;
}

__global__ void k_memh(const float* __restrict__ src, f16* __restrict__ dst, int n8){
  int i = blockIdx.x*blockDim.x + threadIdx.x;
  if (i < n8){
    const float4* s = reinterpret_cast<const float4*>(src) + 2*(size_t)i;
    float4 f0 = s[0], f1 = s[1];
    union { f16 h[8]; float4 v; } u;
    u.h[0]=(f16)f0.x; u.h[1]=(f16)f0.y; u.h[2]=(f16)f0.z; u.h[3]=(f16)f0.w;
    u.h[4]=(f16)f1.x; u.h[5]=(f16)f1.y; u.h[6]=(f16)f1.z; u.h[7]=(f16)f1.w;
    reinterpret_cast<float4*>(dst)[i] = u.v;
  }
}

// keys[b][t][c] = 2log2e * sum_u mem[b][t][u]*W1[c][u]; fp16 out
__global__ __launch_bounds__(256) void k_keys(const float* __restrict__ mem,
      const float* __restrict__ W1t, f16* __restrict__ keys, int T)
{
  const int b = blockIdx.z;
  const int tbase = blockIdx.x * 128;
  const int cbase = blockIdx.y * 128;
  const int tid = threadIdx.x;
  const int rt = tid >> 4, ct = tid & 15;
  const float* memb = mem + (size_t)b*T*UU;

  float acc[8][8];
  #pragma unroll
  for (int i=0;i<8;i++){
    #pragma unroll
    for (int j=0;j<8;j++) acc[i][j]=0.f;
  }
  const float* arow[8];
  #pragma unroll
  for (int i=0;i<8;i++){
    int t = tbase + rt*8 + i;
    arow[i] = memb + (size_t)(t < T ? t : T-1)*UU;
  }
  const float* wcol = W1t + cbase + ct*8;

  for (int k=0;k<UU;k+=4){
    float w8[4][8];
    #pragma unroll
    for (int kk=0;kk<4;kk++){
      float4 lo = *reinterpret_cast<const float4*>(wcol + (size_t)(k+kk)*UU);
      float4 hi = *reinterpret_cast<const float4*>(wcol + (size_t)(k+kk)*UU + 4);
      w8[kk][0]=lo.x; w8[kk][1]=lo.y; w8[kk][2]=lo.z; w8[kk][3]=lo.w;
      w8[kk][4]=hi.x; w8[kk][5]=hi.y; w8[kk][6]=hi.z; w8[kk][7]=hi.w;
    }
    #pragma unroll
    for (int i=0;i<8;i++){
      float4 a = *reinterpret_cast<const float4*>(arow[i] + k);
      float a4[4] = {a.x, a.y, a.z, a.w};
      #pragma unroll
      for (int kk=0;kk<4;kk++){
        #pragma unroll
        for (int j=0;j<8;j++) acc[i][j] += a4[kk]*w8[kk][j];
      }
    }
  }
  #pragma unroll
  for (int i=0;i<8;i++){
    int t = tbase + rt*8 + i;
    if (t < T){
      f16* dst = keys + (size_t)b*T*UU + (size_t)t*UU + cbase + ct*8;
      union { f16 h[8]; float4 v; } u;
      #pragma unroll
      for (int j=0;j<8;j++) u.h[j] = (f16)(acc[i][j]*SCL2LOG2E);
      *reinterpret_cast<float4*>(dst) = u.v;
    }
  }
}

// ---------------- 2-way in-wave K-split GEMV ----------------
__device__ __attribute__((noinline)) void gemv_shfl(
    const h2* __restrict__ W, const h2* __restrict__ in,
    const float* __restrict__ bias, float* __restrict__ destf, h2* __restrict__ desth,
    int K2, int Nf4, int act, int local)
{
  const int lane = local & 63;
  const int half = lane >> 5;
  int col = (local >> 6)*32 + (lane & 31);
  const bool valid = col < Nf4;
  if (!valid) col = 0;
  const int kh = K2 >> 1;
  const float4* w = reinterpret_cast<const float4*>(W) + (size_t)(half*kh)*Nf4 + col;
  const h2* ia = in + half*kh;
  float a0=0.f, a1=0.f, a2=0.f, a3=0.f;
  #pragma unroll 8
  for (int it = 0; it < kh; ++it){
    float4 wp = w[(size_t)it*Nf4];
    h2 a = ia[it];
    const h2* wh = reinterpret_cast<const h2*>(&wp);
    a0 = dot2f(wh[0], a, a0);
    a1 = dot2f(wh[1], a, a1);
    a2 = dot2f(wh[2], a, a2);
    a3 = dot2f(wh[3], a, a3);
  }
  a0 += __shfl_xor(a0, 32, 64);
  a1 += __shfl_xor(a1, 32, 64);
  a2 += __shfl_xor(a2, 32, 64);
  a3 += __shfl_xor(a3, 32, 64);
  if (half == 0 && valid){
    if (bias){
      const float4 bv = reinterpret_cast<const float4*>(bias)[col];
      a0+=bv.x; a1+=bv.y; a2+=bv.z; a3+=bv.w;
    }
    if (act == 1){
      a0=fmaxf(a0,0.f); a1=fmaxf(a1,0.f); a2=fmaxf(a2,0.f); a3=fmaxf(a3,0.f);
    } else if (act == 2){
      const float4 d = reinterpret_cast<float4*>(destf)[col];
      a0+=d.x; a1+=d.y; a2+=d.z; a3+=d.w;
    }
    if (destf){
      float4 r; r.x=a0; r.y=a1; r.z=a2; r.w=a3;
      reinterpret_cast<float4*>(destf)[col] = r;
    }
    if (desth){
      h2 p0; p0[0]=(f16)a0; p0[1]=(f16)a1;
      h2 p1; p1[0]=(f16)a2; p1[1]=(f16)a3;
      desth[2*col] = p0; desth[2*col+1] = p1;
    }
  }
}

// ---------------- 4-way in-wave K-split GEMV (cols/wave = 16) ----------------
__device__ __attribute__((noinline)) void gemv_shfl4(
    const h2* __restrict__ W, const h2* __restrict__ in,
    const float* __restrict__ bias, float* __restrict__ destf, h2* __restrict__ desth,
    int K2, int Nf4, int act, int local)
{
  const int lane = local & 63;
  const int qtr  = lane >> 4;
  int col = (local >> 6)*16 + (lane & 15);
  const bool valid = col < Nf4;
  if (!valid) col = 0;
  const int kq = K2 >> 2;
  const float4* w = reinterpret_cast<const float4*>(W) + (size_t)(qtr*kq)*Nf4 + col;
  const h2* ia = in + qtr*kq;
  float a0=0.f, a1=0.f, a2=0.f, a3=0.f;
  #pragma unroll 8
  for (int it = 0; it < kq; ++it){
    float4 wp = w[(size_t)it*Nf4];
    h2 a = ia[it];
    const h2* wh = reinterpret_cast<const h2*>(&wp);
    a0 = dot2f(wh[0], a, a0);
    a1 = dot2f(wh[1], a, a1);
    a2 = dot2f(wh[2], a, a2);
    a3 = dot2f(wh[3], a, a3);
  }
  a0 += __shfl_xor(a0, 16, 64); a1 += __shfl_xor(a1, 16, 64);
  a2 += __shfl_xor(a2, 16, 64); a3 += __shfl_xor(a3, 16, 64);
  a0 += __shfl_xor(a0, 32, 64); a1 += __shfl_xor(a1, 32, 64);
  a2 += __shfl_xor(a2, 32, 64); a3 += __shfl_xor(a3, 32, 64);
  if (qtr == 0 && valid){
    if (bias){
      const float4 bv = reinterpret_cast<const float4*>(bias)[col];
      a0+=bv.x; a1+=bv.y; a2+=bv.z; a3+=bv.w;
    }
    if (act == 1){
      a0=fmaxf(a0,0.f); a1=fmaxf(a1,0.f); a2=fmaxf(a2,0.f); a3=fmaxf(a3,0.f);
    } else if (act == 2){
      const float4 d = reinterpret_cast<float4*>(destf)[col];
      a0+=d.x; a1+=d.y; a2+=d.z; a3+=d.w;
    }
    if (destf){
      float4 r; r.x=a0; r.y=a1; r.z=a2; r.w=a3;
      reinterpret_cast<float4*>(destf)[col] = r;
    }
    if (desth){
      h2 p0; p0[0]=(f16)a0; p0[1]=(f16)a1;
      h2 p1; p1[0]=(f16)a2; p1[1]=(f16)a3;
      desth[2*col] = p0; desth[2*col+1] = p1;
    }
  }
}

// ---------------- 8-way in-wave K-split GEMV (cols/wave = 8) ----------------
__device__ __attribute__((noinline)) void gemv_shfl8(
    const h2* __restrict__ W, const h2* __restrict__ in,
    const float* __restrict__ bias, float* __restrict__ destf, h2* __restrict__ desth,
    int K2, int Nf4, int act, int local)
{
  const int lane = local & 63;
  const int oct  = lane >> 3;            // 0..7
  int col = (local >> 6)*8 + (lane & 7);
  const bool valid = col < Nf4;
  if (!valid) col = 0;
  const int kq = K2 >> 3;
  const float4* w = reinterpret_cast<const float4*>(W) + (size_t)(oct*kq)*Nf4 + col;
  const h2* ia = in + oct*kq;
  float a0=0.f, a1=0.f, a2=0.f, a3=0.f;
  #pragma unroll 8
  for (int it = 0; it < kq; ++it){
    float4 wp = w[(size_t)it*Nf4];
    h2 a = ia[it];
    const h2* wh = reinterpret_cast<const h2*>(&wp);
    a0 = dot2f(wh[0], a, a0);
    a1 = dot2f(wh[1], a, a1);
    a2 = dot2f(wh[2], a, a2);
    a3 = dot2f(wh[3], a, a3);
  }
  a0 += __shfl_xor(a0,  8, 64); a1 += __shfl_xor(a1,  8, 64);
  a2 += __shfl_xor(a2,  8, 64); a3 += __shfl_xor(a3,  8, 64);
  a0 += __shfl_xor(a0, 16, 64); a1 += __shfl_xor(a1, 16, 64);
  a2 += __shfl_xor(a2, 16, 64); a3 += __shfl_xor(a3, 16, 64);
  a0 += __shfl_xor(a0, 32, 64); a1 += __shfl_xor(a1, 32, 64);
  a2 += __shfl_xor(a2, 32, 64); a3 += __shfl_xor(a3, 32, 64);
  if (oct == 0 && valid){
    if (bias){
      const float4 bv = reinterpret_cast<const float4*>(bias)[col];
      a0+=bv.x; a1+=bv.y; a2+=bv.z; a3+=bv.w;
    }
    if (act == 1){
      a0=fmaxf(a0,0.f); a1=fmaxf(a1,0.f); a2=fmaxf(a2,0.f); a3=fmaxf(a3,0.f);
    } else if (act == 2){
      const float4 d = reinterpret_cast<float4*>(destf)[col];
      a0+=d.x; a1+=d.y; a2+=d.z; a3+=d.w;
    }
    if (destf){
      float4 r; r.x=a0; r.y=a1; r.z=a2; r.w=a3;
      reinterpret_cast<float4*>(destf)[col] = r;
    }
    if (desth){
      h2 p0; p0[0]=(f16)a0; p0[1]=(f16)a1;
      h2 p1; p1[0]=(f16)a2; p1[1]=(f16)a3;
      desth[2*col] = p0; desth[2*col+1] = p1;
    }
  }
}

__device__ __attribute__((noinline)) void gru_gate(
    const float* __restrict__ gi, const float* __restrict__ gh,
    float* __restrict__ h, h2* __restrict__ hh2,
    const float* __restrict__ addsrc, float* __restrict__ sumf,
    h2* __restrict__ sumh, int tid)
{
  if (tid < 128){
    float hn[2], sm[2] = {0.f, 0.f};
    #pragma unroll
    for (int d=0; d<2; ++d){
      int e = 2*tid + d;
      float r = fsig(gi[e] + gh[e]);
      float z = fsig(gi[256+e] + gh[256+e]);
      float n = ftanh(gi[512+e] + r*gh[512+e]);
      hn[d] = (1.f - z)*n + z*h[e];
      h[e] = hn[d];
      if (addsrc){ sm[d] = addsrc[e] + hn[d]; if (sumf) sumf[e] = sm[d]; }
    }
    h2 p; p[0]=(f16)hn[0]; p[1]=(f16)hn[1];
    hh2[tid] = p;
    if (addsrc && sumh){ h2 q; q[0]=(f16)sm[0]; q[1]=(f16)sm[1]; sumh[tid] = q; }
  }
  __syncthreads();
}

// ---------------- persistent decoder: owner (quad0) + attention workers ----------------
__global__ __launch_bounds__(1024) void k_decode(
    const h2* __restrict__ wts, const float* __restrict__ wsf,
    const f16* __restrict__ keysg, const f16* __restrict__ memg,
    float* __restrict__ ctxp, float* __restrict__ esum, float* __restrict__ qbuf,
    int* __restrict__ flagA, int* __restrict__ flagB,
    const float* __restrict__ bp2, const float* __restrict__ vvec,
    const float* __restrict__ ba_ih, const float* __restrict__ ba_hh,
    const float* __restrict__ b1_ih, const float* __restrict__ b1_hh,
    const float* __restrict__ b2_ih, const float* __restrict__ b2_hh,
    const float* __restrict__ bout,
    float* __restrict__ out, int T, int steps)
{
  __shared__ __align__(16) float s_red[4096];
  __shared__ __align__(16) float s_sc[1024];
  __shared__ __align__(16) float s_gi[768];
  __shared__ __align__(16) float s_ghP[2][768];  // parity-buffered Wa_hh@h + ba_hh (prefetched)
  __shared__ __align__(16) float s_gh1[768];
  __shared__ __align__(16) float s_gh2[768];
  __shared__ __align__(16) float s_q[512];       // [0:256]=q', [256:512]=g1in
  __shared__ __align__(16) float s_ha[256];
  __shared__ __align__(16) float s_g1h[256];
  __shared__ __align__(16) float s_g2h[256];
  __shared__ __align__(16) float s_g2in[256];
  __shared__ __align__(16) float s_y[400];
  __shared__ __align__(16) h2    s_hah[128], s_g1hh[128], s_g2hh[128];
  __shared__ __align__(16) h2    s_g1inh[128], s_g2inh[128], s_s2h[128];
  __shared__ __align__(16) h2    s_x1h[128], s_xh[64], s_ctxh[128];
  __shared__ float s_wred[16];

  const int b    = blockIdx.x & 63;
  const int quad = blockIdx.x >> 6;
  const int tid = threadIdx.x;
  const int lane = tid & 63;
  const int wid = tid >> 6;
  const int half_id = lane >> 5;
  const int cl = lane & 31;

  const f16* keyb = keysg + (size_t)b*T*UU;
  const f16* memb = memg  + (size_t)b*T*UU;
  float* outb = out + (size_t)b*80*(steps*RRR);

  // slice bounds: owner ~14%; workers split the rest; even boundaries.
  const int ownEnd = ((T*14)/100) & ~1;
  int tq0, tq1;
  if (quad == 0){ tq0 = 0; tq1 = ownEnd; }
  else {
    tq0 = (quad==1) ? ownEnd : (ownEnd + ((T-ownEnd)*(quad-1))/3) & ~1;
    tq1 = (quad==3) ? T      : (ownEnd + ((T-ownEnd)*quad)/3) & ~1;
  }

  float v8[8], m8[8];
  #pragma unroll
  for (int j=0;j<8;j++){ v8[j] = vvec[cl*8+j]; m8[j] = -2.0f*v8[j]; }
  float sumv = 0.f;
  #pragma unroll
  for (int j=0;j<8;j++) sumv += v8[j];
  #pragma unroll
  for (int o=1;o<32;o<<=1) sumv += __shfl_xor(sumv, o);

  // attention slice: scores -> exp -> ctx partials -> publish (ctxp, esum)
  auto attn_slice = [&](int par){
    {
      float q8[8];
      #pragma unroll
      for (int j=0;j<8;j++) q8[j] = s_q[cl*8+j];
      float rs = 0.f;
      for (int t0 = tq0 + wid*2; t0 < tq1; t0 += 32){
        int t = t0 + half_id;
        fv4 kv = *(reinterpret_cast<const fv4*>(keyb + (size_t)t*UU) + cl);
        const h2* kh = reinterpret_cast<const h2*>(&kv);
        float acc = 0.f;
        #pragma unroll
        for (int p=0;p<4;p++){
          float t0f = (float)kh[p][0] + q8[2*p];
          float t1f = (float)kh[p][1] + q8[2*p+1];
          acc = fmaf(m8[2*p],   frcp(1.f + fexp2(t0f)), acc);
          acc = fmaf(m8[2*p+1], frcp(1.f + fexp2(t1f)), acc);
        }
        #pragma unroll
        for (int o=1;o<32;o<<=1) acc += __shfl_xor(acc, o);
        float e = __expf(sumv + acc);
        if (cl == 0) s_sc[t] = e;
        rs += e;
      }
      rs += __shfl_xor(rs, 32);
      if (lane==0) s_wred[wid] = rs;
    }
    __syncthreads();
    {
      float c8[8] = {0.f,0.f,0.f,0.f,0.f,0.f,0.f,0.f};
      for (int t0 = tq0 + wid*2; t0 < tq1; t0 += 32){
        int t = t0 + half_id;
        float wgt = s_sc[t];
        fv4 mv = *(reinterpret_cast<const fv4*>(memb + (size_t)t*UU) + cl);
        const h2* mh = reinterpret_cast<const h2*>(&mv);
        #pragma unroll
        for (int p=0;p<4;p++){
          c8[2*p  ] += wgt*(float)mh[p][0];
          c8[2*p+1] += wgt*(float)mh[p][1];
        }
      }
      #pragma unroll
      for (int j=0;j<8;j++) c8[j] += __shfl_xor(c8[j], 32);
      if (half_id == 0){
        float4 lo; lo.x=c8[0]; lo.y=c8[1]; lo.z=c8[2]; lo.w=c8[3];
        float4 hi; hi.x=c8[4]; hi.y=c8[5]; hi.z=c8[6]; hi.w=c8[7];
        *reinterpret_cast<float4*>(s_red + wid*256 + cl*8)     = lo;
        *reinterpret_cast<float4*>(s_red + wid*256 + cl*8 + 4) = hi;
      }
    }
    __syncthreads();
    {
      float* cp = ctxp + (((size_t)b*2 + par)*NQUAD + quad)*256;
      if (tid < 128){
        float a = 0.f, c = 0.f;
        #pragma unroll
        for (int w=0; w<16; ++w){
          a += s_red[w*256 + 2*tid];
          c += s_red[w*256 + 2*tid+1];
        }
        cp[2*tid]   = a;
        cp[2*tid+1] = c;
      }
      if (tid == 0){
        float tot = 0.f;
        #pragma unroll
        for (int w=0; w<16; ++w) tot += s_wred[w];
        esum[((size_t)b*2 + par)*NQUAD + quad] = tot;
      }
    }
    __syncthreads();
  };

  if (quad != 0){
    // ---------------- worker: attention only ----------------
    for (int step = 0; step < steps; ++step){
      const int par = step & 1;
      if (tid == 0) wait_flag(flagA + b*256 + step, 1);
      __syncthreads();
      if (tid < 256)
        s_q[tid] = __hip_atomic_load(qbuf + ((size_t)b*2 + par)*256 + tid,
                                     __ATOMIC_RELAXED, __HIP_MEMORY_SCOPE_AGENT);
      __syncthreads();
      attn_slice(par);
      if (tid == 0){
        __threadfence();
        __hip_atomic_fetch_add(flagB + b*256 + step, 1, __ATOMIC_RELEASE, __HIP_MEMORY_SCOPE_AGENT);
      }
      __syncthreads();
    }
    return;
  }

  // ---------------- owner ----------------
  if (tid < 128){
    s_ha[2*tid]=0.f; s_ha[2*tid+1]=0.f;
    s_g1h[2*tid]=0.f; s_g1h[2*tid+1]=0.f;
    s_g2h[2*tid]=0.f; s_g2h[2*tid+1]=0.f;
    h2 z; z[0]=(f16)0.f; z[1]=(f16)0.f;
    s_hah[tid]=z; s_g1hh[tid]=z; s_g2hh[tid]=z;
    // x1(0) = relu(bp1) from the init buffer at OF_BFUSE+256
    const float* ix = wsf + OF_BFUSE + 256;
    h2 p; p[0] = (f16)ix[2*tid]; p[1] = (f16)ix[2*tid+1];
    s_x1h[tid] = p;
  }
  for (int i = tid; i < 768; i += 1024) s_ghP[0][i] = ba_hh[i];
  __syncthreads();

  for (int step = 0; step < steps; ++step){
    const int par = step & 1;
    // part1: prenet2 (x1 -> x): 8-way, 256 thr, 2 latency batches
    if (tid < 256) gemv_shfl8(wts+O_WP2T, s_x1h, bp2, nullptr, s_xh, 128, 32, 1, tid);
    __syncthreads();
    // WAIH (K2=64): 4-way, 768 thr, 2 batches
    if (tid < 768) gemv_shfl4(wts+O_WAIH, s_xh, ba_ih, s_gi, nullptr, 64, 192, 0, tid);
    __syncthreads();
    // gate_a with PREFETCHED gha (s_ghP[par])
    gru_gate(s_gi, s_ghP[par], s_ha, s_hah, nullptr, nullptr, nullptr, tid);
    // WQP: q' | g1in: 8-way, all 1024 thr, 2 batches
    gemv_shfl8(wts+O_WQP, s_hah, wsf+OF_BQP, s_q, nullptr, 128, 128, 0, tid);
    __syncthreads();
    // publish q', release flag A
    if (tid < 256)
      qbuf[((size_t)b*2 + par)*256 + tid] = s_q[tid];
    __syncthreads();
    if (tid == 0){
      __threadfence();
      __hip_atomic_fetch_add(flagA + b*256 + step, 1, __ATOMIC_RELEASE, __HIP_MEMORY_SCOPE_AGENT);
    }
    // overlap: WAHH prefetch for NEXT step (d_t(s) just computed)
    if (tid < 768) gemv_shfl4(wts+O_WAHH, s_hah, ba_hh, s_ghP[par^1], nullptr, 128, 192, 0, tid);
    // W1HH || W2HH (needed at tail gates)
    if (tid < 384)      gemv_shfl(wts+O_W1HH, s_g1hh, b1_hh, s_gh1, nullptr, 128, 192, 0, tid);
    else if (tid < 768) gemv_shfl(wts+O_W2HH, s_g2hh, b2_hh, s_gh2, nullptr, 128, 192, 0, tid-384);
    attn_slice(par);
    if (tid == 0){
      __threadfence();
      __hip_atomic_fetch_add(flagB + b*256 + step, 1, __ATOMIC_RELEASE, __HIP_MEMORY_SCOPE_AGENT);
      wait_flag(flagB + b*256 + step, NQUAD);
    }
    __syncthreads();
    // combine
    if (tid < 128){
      const float* cp0 = ctxp + ((size_t)b*2 + par)*NQUAD*256;
      const float* es0 = esum + ((size_t)b*2 + par)*NQUAD;
      float es = 0.f;
      #pragma unroll
      for (int q4=0;q4<NQUAD;q4++)
        es += __hip_atomic_load(&es0[q4], __ATOMIC_RELAXED, __HIP_MEMORY_SCOPE_AGENT);
      float inv = frcp(es);
      float a = 0.f, c = 0.f;
      #pragma unroll
      for (int q4=0;q4<NQUAD;q4++){
        a += __hip_atomic_load(&cp0[q4*256 + 2*tid],   __ATOMIC_RELAXED, __HIP_MEMORY_SCOPE_AGENT);
        c += __hip_atomic_load(&cp0[q4*256 + 2*tid+1], __ATOMIC_RELAXED, __HIP_MEMORY_SCOPE_AGENT);
      }
      h2 p; p[0]=(f16)(a*inv); p[1]=(f16)(c*inv);
      s_ctxh[tid] = p;
    }
    __syncthreads();
    // WPC: 8-way, 512 thr, 2 batches
    if (tid < 512) gemv_shfl8(wts+O_WPC, s_ctxh, nullptr, s_q+256, s_g1inh, 128, 64, 2, tid);
    __syncthreads();
    // W1IH: 4-way (width 192)
    if (tid < 768) gemv_shfl4(wts+O_W1IH, s_g1inh, b1_ih, s_gi, nullptr, 128, 192, 0, tid);
    __syncthreads();
    gru_gate(s_gi, s_gh1, s_g1h, s_g1hh, s_q+256, s_g2in, s_g2inh, tid);
    // W2IH: 4-way (width 192)
    if (tid < 768) gemv_shfl4(wts+O_W2IH, s_g2inh, b2_ih, s_gi, nullptr, 128, 192, 0, tid);
    __syncthreads();
    gru_gate(s_gi, s_gh2, s_g2h, s_g2hh, s_g2in, nullptr, s_s2h, tid);
    // WFUSE (recurrence-critical) 8-way 512 thr || WOUT (output only) 4-way 448 thr
    if (tid < 512)      gemv_shfl8(wts+O_WFUSE, s_s2h, wsf+OF_BFUSE, nullptr, s_x1h, 128, 64, 1, tid);
    else if (tid < 960) gemv_shfl4(wts+O_WOUT,  s_s2h, bout, s_y, nullptr, 128, 100, 0, tid-512);
    __syncthreads();
    // scatter
    if (tid < 400){
      float val = s_y[tid];
      int mel = tid / 5, rr = tid - mel*5;
      __builtin_nontemporal_store(val, &outb[(size_t)mel*(steps*RRR) + step*RRR + rr]);
    }
    __syncthreads();
  }
}

extern "C" void kernel_launch(void* const* d_in, const int* in_sizes, int n_in,
                              void* d_out, int out_size, void* d_ws, size_t ws_size,
                              hipStream_t stream)
{
  const float* mem  = (const float*)d_in[0];
  const float* Wp1  = (const float*)d_in[1];
  const float* bp1  = (const float*)d_in[2];
  const float* Wp2  = (const float*)d_in[3];
  const float* bp2  = (const float*)d_in[4];
  const float* W1   = (const float*)d_in[5];
  const float* W2   = (const float*)d_in[6];
  const float* vv   = (const float*)d_in[7];
  const float* Wa_ih= (const float*)d_in[8];
  const float* Wa_hh= (const float*)d_in[9];
  const float* ba_ih= (const float*)d_in[10];
  const float* ba_hh= (const float*)d_in[11];
  const float* W1_ih= (const float*)d_in[12];
  const float* W1_hh= (const float*)d_in[13];
  const float* b1_ih= (const float*)d_in[14];
  const float* b1_hh= (const float*)d_in[15];
  const float* W2_ih= (const float*)d_in[16];
  const float* W2_hh= (const float*)d_in[17];
  const float* b2_ih= (const float*)d_in[18];
  const float* b2_hh= (const float*)d_in[19];
  const float* Wproj= (const float*)d_in[20];
  const float* bproj= (const float*)d_in[21];
  const float* Wout = (const float*)d_in[22];
  const float* bout = (const float*)d_in[23];

  h2*  wsH2 = (h2*)d_ws;
  f16* wsF16= (f16*)d_ws;
  float* wsF = (float*)d_ws;
  int*  wsI = (int*)d_ws;
  int T = in_sizes[0] / (BB*UU);
  int steps = T / RRR;

  auto tr = [&](const float* src, int srcK, int kbase, size_t off, int N, int K,
                int Ntot, int coloff, float scale){
    int total = N*(K/2);
    k_tr_hx<<<dim3((total+255)/256), dim3(256), 0, stream>>>(
        src, srcK, kbase, wsH2 + off, N, K, Ntot, coloff, scale);
  };
  tr(Wp2,   256, 0, O_WP2T, 128, 256, 128, 0, 1.f);
  tr(Wa_ih, 128, 0, O_WAIH, 768, 128, 768, 0, 1.f);
  tr(Wa_hh, 256, 0, O_WAHH, 768, 256, 768, 0, 1.f);
  tr(W2,    256, 0, O_WQP,  256, 256, 512, 0, SCL2LOG2E);
  tr(Wproj, 512, 0, O_WQP,  256, 256, 512, 256, 1.f);
  tr(Wproj, 512, 256, O_WPC, 256, 256, 256, 0, 1.f);
  tr(W1_ih, 256, 0, O_W1IH, 768, 256, 768, 0, 1.f);
  tr(W1_hh, 256, 0, O_W1HH, 768, 256, 768, 0, 1.f);
  tr(W2_ih, 256, 0, O_W2IH, 768, 256, 768, 0, 1.f);
  tr(W2_hh, 256, 0, O_W2HH, 768, 256, 768, 0, 1.f);
  tr(Wout,  256, 0, O_WOUT, 400, 256, 400, 0, 1.f);

  k_biasqp<<<dim3(2), dim3(256), 0, stream>>>(bproj, wsF + OF_BQP);
  k_transpose<<<dim3((256*256+255)/256), dim3(256), 0, stream>>>(W1, wsF + OF_W1T, 256, 256);
  k_zero<<<dim3(128), dim3(256), 0, stream>>>(wsI + OI_FLAGA, 2*64*256);
  k_fuse_w<<<dim3((256*128+255)/256), dim3(256), 0, stream>>>(Wp1, Wout, wsH2 + O_WFUSE);
  k_fuse_b<<<dim3(1), dim3(256), 0, stream>>>(Wp1, bout, bp1, wsF + OF_BFUSE);
  k_initx1<<<dim3(1), dim3(256), 0, stream>>>(bp1, wsF + OF_BFUSE + 256);

  int n8 = (BB*T*UU)/8;
  k_memh<<<dim3((n8+255)/256), dim3(256), 0, stream>>>(mem, wsF16 + OH_MEM, n8);
  k_keys<<<dim3((T+127)/128, UU/128, BB), dim3(256), 0, stream>>>(mem, wsF + OF_W1T, wsF16 + OH_KEYS, T);

  k_decode<<<dim3(BB*NQUAD), dim3(1024), 0, stream>>>(wsH2, wsF,
      wsF16 + OH_KEYS, wsF16 + OH_MEM,
      wsF + OF_CTXP, wsF + OF_ESUM, wsF + OF_QB,
      wsI + OI_FLAGA, wsI + OI_FLAGB,
      bp2, vv, ba_ih, ba_hh, b1_ih, b1_hh, b2_ih, b2_hh, bout,
      (float*)d_out, T, steps);
}